// Round 9
// baseline (30.064 us; speedup 1.0000x reference)
//
#include <hip/hip_runtime.h>

#define NNODE 64
#define KLEN  512
#define WIN   5
#define NT    508           // KLEN - WIN + 1
#define EMB   64
#define NDST  63

// workspace layout (floats): xl[t][n][d] then A[t][n]
#define XL_OFF 0
#define A_OFF  ((size_t)NT * NNODE * EMB)

// xr LDS swizzle (T2-style): row stride 64 floats (256B, no pad); 4-float
// group g of row n stored at slot g^(n&7)  (byte_off ^= (n&7)<<4).
// Read of row n=lane, group g: banks 4*((g^(lane&7))&7) -> 8 consecutive
// lanes cover all 8 bank-windows exactly once => conflict-free b128.
__device__ __forceinline__ int xr_idx(int n, int d) {
    return n * EMB + ((((d >> 2) ^ (n & 7)) << 2) | (d & 3));
}

// ---------------- K1-lite: conv + xl + A only (unchanged from R8) ----------------
__global__ __launch_bounds__(256) void precompute_xl(
    const float* __restrict__ x,
    const float* __restrict__ conv_w,
    const float* __restrict__ conv_b,
    const float* __restrict__ lin_l_w,
    const float* __restrict__ lin_l_b,
    const float* __restrict__ att,
    float* __restrict__ ws)
{
    const int bx = blockIdx.x;
    const int t  = (bx & 7) * 64 + (bx >> 3);
    if (t >= NT) return;
    const int tid  = threadIdx.x;
    const int lane = tid & 63;
    const int wave = tid >> 6;

    __shared__ float h_s[NNODE][9];

    for (int idx = tid; idx < NNODE * WIN; idx += 256) {
        const int n = idx / WIN;
        const int w = idx % WIN;
        const int base = t + w - 2;
        float acc = conv_b[0];
        #pragma unroll
        for (int j = 0; j < WIN; ++j) {
            const int k = base + j;
            const float xv = (k >= 0 && k < KLEN) ? x[n * KLEN + k] : 0.f;
            acc = fmaf(conv_w[j], xv, acc);
        }
        h_s[n][w] = 1.f / (1.f + __expf(-acc));
    }
    __syncthreads();

    {
        float lw[WIN];
        #pragma unroll
        for (int w = 0; w < WIN; ++w) lw[w] = lin_l_w[lane * WIN + w];
        const float lb = lin_l_b[lane];
        float* xl_ws = ws + XL_OFF + (size_t)t * NNODE * EMB;
        #pragma unroll
        for (int k = 0; k < 16; ++k) {
            const int n = wave + 4 * k;
            float xl = lb;
            #pragma unroll
            for (int w = 0; w < WIN; ++w)
                xl = fmaf(lw[w], h_s[n][w], xl);
            xl_ws[n * EMB + lane] = xl;              // coalesced
        }
    }

    if (wave == 0) {
        const float attv = att[lane];
        float c[WIN], c0;
        #pragma unroll
        for (int w = 0; w < WIN; ++w) {
            float v = attv * lin_l_w[lane * WIN + w];
            #pragma unroll
            for (int off = 32; off; off >>= 1) v += __shfl_xor(v, off);
            c[w] = v;
        }
        {
            float v = attv * lin_l_b[lane];
            #pragma unroll
            for (int off = 32; off; off >>= 1) v += __shfl_xor(v, off);
            c0 = v;
        }
        float acc = c0;
        #pragma unroll
        for (int w = 0; w < WIN; ++w)
            acc = fmaf(c[w], h_s[lane][w], acc);
        ws[A_OFF + (size_t)t * NNODE + lane] = acc;
    }
}

// ---------------- K2: as R8, with swizzled xr_s (single change) ----------------
__global__ __launch_bounds__(256) void attn_main(
    const float* __restrict__ x,
    const float* __restrict__ conv_w,
    const float* __restrict__ conv_b,
    const float* __restrict__ lin_r_w,
    const float* __restrict__ lin_r_b,
    const float* __restrict__ att,
    const float* __restrict__ ws,
    float* __restrict__ out)          // [ETOT][NT]
{
    const int bx = blockIdx.x;
    const int t  = (bx & 7) * 64 + (bx >> 3);
    if (t >= NT) return;
    const int sg   = blockIdx.y;
    const int tid  = threadIdx.x;
    const int lane = tid & 63;
    const int wave = tid >> 6;

    __shared__ float h_s[NNODE][9];
    __shared__ float xr_s[NNODE * EMB];   // swizzled, stride 64, no pad

    for (int idx = tid; idx < NNODE * WIN; idx += 256) {
        const int n = idx / WIN;
        const int w = idx % WIN;
        const int base = t + w - 2;
        float acc = conv_b[0];
        #pragma unroll
        for (int j = 0; j < WIN; ++j) {
            const int k = base + j;
            const float xv = (k >= 0 && k < KLEN) ? x[n * KLEN + k] : 0.f;
            acc = fmaf(conv_w[j], xv, acc);
        }
        h_s[n][w] = 1.f / (1.f + __expf(-acc));
    }
    __syncthreads();

    // xr[n][lane] -> swizzled LDS (lane = d, wave strides nodes)
    {
        float rw[WIN];
        #pragma unroll
        for (int w = 0; w < WIN; ++w) rw[w] = lin_r_w[lane * WIN + w];
        const float rb = lin_r_b[lane];
        #pragma unroll
        for (int k = 0; k < 16; ++k) {
            const int n = wave + 4 * k;
            float xr = rb;
            #pragma unroll
            for (int w = 0; w < WIN; ++w)
                xr = fmaf(rw[w], h_s[n][w], xr);
            xr_s[xr_idx(n, lane)] = xr;          // 64-float row permutation: 2-way max
        }
    }

    const int wu = __builtin_amdgcn_readfirstlane(wave);
    const int s0 = sg * 16 + wu * 4;
    const float* xl_g = ws + XL_OFF + (size_t)t * NNODE * EMB + (size_t)s0 * EMB;
    const float* A_g  = ws + A_OFF + (size_t)t * NNODE + s0;

    __syncthreads();

    // main loop (lane = dst r): swizzled conflict-free b128 + uniform s_loads
    float accm[4] = {0.f, 0.f, 0.f, 0.f};
    float accB = 0.f;
    #pragma unroll
    for (int d0 = 0; d0 < EMB; d0 += 4) {
        const float4 xr4 = *(const float4*)&xr_s[xr_idx(lane, d0)];
        const float a0 = att[d0 + 0];                      // uniform -> s_load
        const float a1 = att[d0 + 1];
        const float a2 = att[d0 + 2];
        const float a3 = att[d0 + 3];
        accB = fmaf(a0, xr4.x, accB);
        accB = fmaf(a1, xr4.y, accB);
        accB = fmaf(a2, xr4.z, accB);
        accB = fmaf(a3, xr4.w, accB);
        #pragma unroll
        for (int p = 0; p < 4; ++p) {
            const float* xlp = xl_g + p * EMB + d0;        // uniform -> s_load
            float z;
            z = xlp[0] + xr4.x; accm[p] = fmaf(a0, fabsf(z), accm[p]);
            z = xlp[1] + xr4.y; accm[p] = fmaf(a1, fabsf(z), accm[p]);
            z = xlp[2] + xr4.z; accm[p] = fmaf(a2, fabsf(z), accm[p]);
            z = xlp[3] + xr4.w; accm[p] = fmaf(a3, fabsf(z), accm[p]);
        }
    }

    // softmax over 63 active lanes (no max-shift), e-major write
    float ex[4];
    #pragma unroll
    for (int p = 0; p < 4; ++p) {
        const int s = s0 + p;
        const float alpha = fmaf(0.4f, accm[p], 0.6f * (A_g[p] + accB));
        ex[p] = (lane == s) ? 0.f : __expf(alpha);
    }
    float sum[4];
    #pragma unroll
    for (int p = 0; p < 4; ++p) sum[p] = ex[p];
    #pragma unroll
    for (int off = 32; off; off >>= 1) {
        #pragma unroll
        for (int p = 0; p < 4; ++p) sum[p] += __shfl_xor(sum[p], off);
    }
    #pragma unroll
    for (int p = 0; p < 4; ++p) {
        const int s = s0 + p;
        const float res = ex[p] * __builtin_amdgcn_rcpf(sum[p] + 1e-16f);
        if (lane != s) {
            const int j = lane - (lane > s ? 1 : 0);
            out[(size_t)(s * NDST + j) * NT + t] = res;
        }
    }
}

extern "C" void kernel_launch(void* const* d_in, const int* in_sizes, int n_in,
                              void* d_out, int out_size, void* d_ws, size_t ws_size,
                              hipStream_t stream)
{
    const float* x       = (const float*)d_in[0];
    // d_in[1] = edge_index: fixed full graph, hardcoded.
    const float* conv_w  = (const float*)d_in[2];
    const float* conv_b  = (const float*)d_in[3];
    const float* lin_l_w = (const float*)d_in[4];
    const float* lin_l_b = (const float*)d_in[5];
    const float* lin_r_w = (const float*)d_in[6];
    const float* lin_r_b = (const float*)d_in[7];
    const float* att     = (const float*)d_in[8];
    float* out = (float*)d_out;
    float* ws  = (float*)d_ws;   // ~8.4 MB used

    precompute_xl<<<dim3(512), 256, 0, stream>>>(x, conv_w, conv_b,
        lin_l_w, lin_l_b, att, ws);
    attn_main<<<dim3(512, 4), 256, 0, stream>>>(x, conv_w, conv_b,
        lin_r_w, lin_r_b, att, ws, out);
}